// Round 4
// baseline (319.579 us; speedup 1.0000x reference)
//
#include <hip/hip_runtime.h>

// Problem constants
#define NB   2
#define ND   16
#define NH   64
#define DHW  65536       // D*H*W
#define HW   4096        // H*W
#define CDHW 16777216    // C*D*H*W

// LDS regions (bytes), total 40960 -> 4 blocks/CU (160 KiB exactly)
// R1 [0,16384):      Xth[64][128B] swz + Xtl[64][128B] swz  ->  Ah/Al same layout
// R2 [16384,32768):  Xlin[64][64] f32  ->  Kh/Kl[64][32] ushort  ->  Vb 4 waves x 4096 B
// R3 [32768,40960):  Qh[64][32], Ql[64][32] ushort
#define OFF_XTH 0
#define OFF_XTL 8192
#define OFF_AH  0
#define OFF_AL  8192
#define OFF_R2  16384
#define OFF_KH  16384
#define OFF_KL  20480
#define OFF_QH  32768
#define OFF_QL  36864
#define SMEM_BYTES 40960

typedef __attribute__((ext_vector_type(4))) float f32x4;
typedef __attribute__((ext_vector_type(8))) short bf16x8;
typedef unsigned short ushort_t;

#define MFMA16(a, b, c) __builtin_amdgcn_mfma_f32_16x16x32_bf16((a), (b), (c), 0, 0, 0)

// ws layout (ushort elements)
#define WS_WQH 0
#define WS_WQL 8192
#define WS_WKH 16384
#define WS_WKL 24576
#define WS_WVH 32768
#define WS_WVL 98304
#define WS_NEED_BYTES 327680

__device__ __forceinline__ void split_val(float f, short& h, short& l) {
  unsigned int u = __builtin_bit_cast(unsigned int, f);
  h = (short)(unsigned short)(u >> 16);
  float fh = __builtin_bit_cast(float, u & 0xffff0000u);
  float r = f - fh;
  l = (short)(unsigned short)(__builtin_bit_cast(unsigned int, r) >> 16);
}

__device__ __forceinline__ void load_split8(const float* __restrict__ p, bf16x8& h8, bf16x8& l8) {
  float4 a = *(const float4*)p;
  float4 b = *(const float4*)(p + 4);
  float f[8] = {a.x, a.y, a.z, a.w, b.x, b.y, b.z, b.w};
#pragma unroll
  for (int j = 0; j < 8; ++j) {
    short hh, ll;
    split_val(f[j], hh, ll);
    h8[j] = hh; l8[j] = ll;
  }
}

// byte offset in a [rows][128 B] XOR-swizzled tile (16 B slot granularity)
__device__ __forceinline__ int swzb(int row, int colb) {
  return row * 128 + (((colb) & ~15) ^ ((row & 7) << 4)) + ((colb) & 15);
}

// ---------------- weight pre-split kernel ----------------
__global__ void prep_w(const float* __restrict__ Wq, const float* __restrict__ Wk,
                       const float* __restrict__ Wv, ushort_t* __restrict__ ws) {
  int idx = blockIdx.x * 256 + threadIdx.x;
  const float* src; int off; ushort_t *H, *L;
  if (idx < 8192)       { src = Wq; off = idx;         H = ws + WS_WQH; L = ws + WS_WQL; }
  else if (idx < 16384) { src = Wk; off = idx - 8192;  H = ws + WS_WKH; L = ws + WS_WKL; }
  else if (idx < 81920) { src = Wv; off = idx - 16384; H = ws + WS_WVH; L = ws + WS_WVL; }
  else return;
  short h, l;
  split_val(src[off], h, l);
  H[off] = (ushort_t)h;
  L[off] = (ushort_t)l;
}

// ---------------- main kernel ----------------
template<bool PW>
__global__ __launch_bounds__(256, 4) void xattn(
    const float* __restrict__ x1, const float* __restrict__ x2,
    const float* __restrict__ Wq, const float* __restrict__ bq,
    const float* __restrict__ Wk, const float* __restrict__ bk,
    const float* __restrict__ Wv, const float* __restrict__ bv,
    const ushort_t* __restrict__ wsp, float* __restrict__ out)
{
  __shared__ char smem[SMEM_BYTES];
  char*     XthB = smem + OFF_XTH;               // [64][128B] swz (col = channel*2)
  char*     XtlB = smem + OFF_XTL;
  float*    Xlin = (float*)(smem + OFF_R2);      // [64][64] f32
  ushort_t* Kh   = (ushort_t*)(smem + OFF_KH);   // [64][32]
  ushort_t* Kl   = (ushort_t*)(smem + OFF_KL);
  char*     AhB  = smem + OFF_AH;                // [64][128B] swz (col = y*2)
  char*     AlB  = smem + OFF_AL;
  ushort_t* Qh   = (ushort_t*)(smem + OFF_QH);   // [64][32]
  ushort_t* Ql   = (ushort_t*)(smem + OFF_QL);

  const int tid  = threadIdx.x;
  const int lane = tid & 63;
  const int wv   = tid >> 6;
  const int l15  = lane & 15;
  const int g    = lane >> 4;

  const int grp = blockIdx.x;
  const int b   = grp >> 10;
  const int rem = grp & 1023;
  const int d   = rem >> 6;
  const int h   = rem & 63;
  const size_t base = (size_t)b * CDHW + (size_t)d * HW + (size_t)h * 64;

  const ushort_t* WqH = wsp + WS_WQH;
  const ushort_t* WqL = wsp + WS_WQL;
  const ushort_t* WkH = wsp + WS_WKH;
  const ushort_t* WkL = wsp + WS_WKL;
  const ushort_t* WvH = wsp + WS_WVH;
  const ushort_t* WvL = wsp + WS_WVL;

  const float* x1p = x1 + base;
  const float* x2p = x2 + base;

  // staging registers: 4 x float4 per wave (16 channels x this lane-group's 4 x-positions)
  float4 pf[4];
  auto issue_pf = [&](const float* __restrict__ src) {
#pragma unroll
    for (int i = 0; i < 4; ++i) {
      int ch = 16 * wv + g + 4 * i;
      pf[i] = *(const float4*)(src + (size_t)ch * DHW + 4 * l15);
    }
  };
  auto write_xlin = [&]() {
#pragma unroll
    for (int i = 0; i < 4; ++i) {
      int ch = 16 * wv + g + 4 * i;
      *(float4*)&Xlin[ch * 64 + 4 * l15] = pf[i];
    }
  };
  // transpose + split the wave's 16 channels into swizzled Xth/Xtl (row = lane = x)
  auto passB = [&]() {
#pragma unroll
    for (int bb = 0; bb < 2; ++bb) {
      int c0 = 16 * wv + 8 * bb;
      bf16x8 h8, l8;
#pragma unroll
      for (int j = 0; j < 8; ++j) {
        float f = Xlin[(c0 + j) * 64 + lane];
        short hh, ll;
        split_val(f, hh, ll);
        h8[j] = hh; l8[j] = ll;
      }
      *(bf16x8*)(XthB + swzb(lane, c0 * 2)) = h8;
      *(bf16x8*)(XtlB + swzb(lane, c0 * 2)) = l8;
    }
  };
  // swizzled fragment read: row = x, ko = channel offset (k-slice)
  auto ldsx = [&](const char* B, int row, int ko) -> bf16x8 {
    return *(const bf16x8*)(B + swzb(row, ko * 2));
  };

  // ===== loop 1: stream x1 c-tiles, accumulate Q^T =====
  {
    f32x4 qacc[2];
#pragma unroll
    for (int mt = 0; mt < 2; ++mt) {
      int r0 = mt * 16 + 4 * g;
      qacc[mt] = (f32x4){bq[r0], bq[r0 + 1], bq[r0 + 2], bq[r0 + 3]};
    }
    issue_pf(x1p);
    write_xlin();
    __syncthreads();                         // Xlin(t0) visible
    for (int t = 0; t < 4; ++t) {
      passB();
      __syncthreads();                       // Xth(t) visible; Xlin(t) free
      issue_pf(t < 3 ? x1p + (size_t)(t + 1) * 64 * DHW : x2p);
#pragma unroll
      for (int ks = 0; ks < 2; ++ks) {
        const int ko = ks * 32 + 8 * g;
        const int kg = t * 64 + ko;
        bf16x8 bh = ldsx(XthB, 16 * wv + l15, ko);
        bf16x8 bl = ldsx(XtlB, 16 * wv + l15, ko);
#pragma unroll
        for (int mt = 0; mt < 2; ++mt) {
          bf16x8 wh, wl;
          if constexpr (PW) {
            wh = *(const bf16x8*)&WqH[(size_t)(mt * 16 + l15) * 256 + kg];
            wl = *(const bf16x8*)&WqL[(size_t)(mt * 16 + l15) * 256 + kg];
          } else {
            load_split8(Wq + (size_t)(mt * 16 + l15) * 256 + kg, wh, wl);
          }
          qacc[mt] = MFMA16(wh, bh, qacc[mt]);
          qacc[mt] = MFMA16(wh, bl, qacc[mt]);
          qacc[mt] = MFMA16(wl, bh, qacc[mt]);
        }
      }
      write_xlin();                          // next tile -> Xlin (vmcnt waits here)
      __syncthreads();                       // Xlin(t+1) visible; Xth(t) free
    }
    // write Q split to R3
    const int x = 16 * wv + l15;
#pragma unroll
    for (int mt = 0; mt < 2; ++mt)
#pragma unroll
      for (int r = 0; r < 4; ++r) {
        short hh, ll;
        split_val(qacc[mt][r], hh, ll);
        Qh[x * 32 + mt * 16 + 4 * g + r] = (ushort_t)hh;
        Ql[x * 32 + mt * 16 + 4 * g + r] = (ushort_t)ll;
      }
  }

  // ===== loop 2: stream x2 c-tiles, accumulate K^T + V =====
  f32x4 vacc[4][4];
  {
    f32x4 kacc[2];
#pragma unroll
    for (int mt = 0; mt < 2; ++mt) {
      int r0 = mt * 16 + 4 * g;
      kacc[mt] = (f32x4){bk[r0], bk[r0 + 1], bk[r0 + 2], bk[r0 + 3]};
    }
#pragma unroll
    for (int mt = 0; mt < 4; ++mt) {
      int r0 = 64 * wv + mt * 16 + 4 * g;
      f32x4 bb = (f32x4){bv[r0], bv[r0 + 1], bv[r0 + 2], bv[r0 + 3]};
#pragma unroll
      for (int nt = 0; nt < 4; ++nt) vacc[mt][nt] = bb;
    }
    for (int t = 0; t < 4; ++t) {
      passB();
      __syncthreads();
      if (t < 3) issue_pf(x2p + (size_t)(t + 1) * 64 * DHW);
#pragma unroll
      for (int ks = 0; ks < 2; ++ks) {
        const int ko = ks * 32 + 8 * g;
        const int kg = t * 64 + ko;
        bf16x8 xh[4], xl[4];
#pragma unroll
        for (int nt = 0; nt < 4; ++nt) {
          xh[nt] = ldsx(XthB, nt * 16 + l15, ko);
          xl[nt] = ldsx(XtlB, nt * 16 + l15, ko);
        }
        // K
        {
          bf16x8 bh = ldsx(XthB, 16 * wv + l15, ko);
          bf16x8 bl = ldsx(XtlB, 16 * wv + l15, ko);
#pragma unroll
          for (int mt = 0; mt < 2; ++mt) {
            bf16x8 wh, wl;
            if constexpr (PW) {
              wh = *(const bf16x8*)&WkH[(size_t)(mt * 16 + l15) * 256 + kg];
              wl = *(const bf16x8*)&WkL[(size_t)(mt * 16 + l15) * 256 + kg];
            } else {
              load_split8(Wk + (size_t)(mt * 16 + l15) * 256 + kg, wh, wl);
            }
            kacc[mt] = MFMA16(wh, bh, kacc[mt]);
            kacc[mt] = MFMA16(wh, bl, kacc[mt]);
            kacc[mt] = MFMA16(wl, bh, kacc[mt]);
          }
        }
        // V
        __builtin_amdgcn_s_setprio(1);
#pragma unroll
        for (int mt = 0; mt < 4; ++mt) {
          bf16x8 wh, wl;
          if constexpr (PW) {
            wh = *(const bf16x8*)&WvH[(size_t)(64 * wv + mt * 16 + l15) * 256 + kg];
            wl = *(const bf16x8*)&WvL[(size_t)(64 * wv + mt * 16 + l15) * 256 + kg];
          } else {
            load_split8(Wv + (size_t)(64 * wv + mt * 16 + l15) * 256 + kg, wh, wl);
          }
#pragma unroll
          for (int nt = 0; nt < 4; ++nt) {
            vacc[mt][nt] = MFMA16(wh, xh[nt], vacc[mt][nt]);
            vacc[mt][nt] = MFMA16(wh, xl[nt], vacc[mt][nt]);
            vacc[mt][nt] = MFMA16(wl, xh[nt], vacc[mt][nt]);
          }
        }
        __builtin_amdgcn_s_setprio(0);
      }
      if (t < 3) {
        write_xlin();
      } else {
        // write K split to Kh/Kl (overlays Xlin; all passB reads finished at last sync)
        const int y = 16 * wv + l15;
#pragma unroll
        for (int mt = 0; mt < 2; ++mt)
#pragma unroll
          for (int r = 0; r < 4; ++r) {
            short hh, ll;
            split_val(kacc[mt][r], hh, ll);
            Kh[y * 32 + mt * 16 + 4 * g + r] = (ushort_t)hh;
            Kl[y * 32 + mt * 16 + 4 * g + r] = (ushort_t)ll;
          }
      }
      __syncthreads();
    }
  }

  // ===== phase 3: A = Q^T K (64x64) -> swizzled Ah/Al in R1 (Xth/Xtl dead) =====
  {
    const int y = 16 * wv + l15;
    bf16x8 kh = *(const bf16x8*)&Kh[y * 32 + 8 * g];
    bf16x8 kl = *(const bf16x8*)&Kl[y * 32 + 8 * g];
    f32x4 acc[4];
#pragma unroll
    for (int mt = 0; mt < 4; ++mt) acc[mt] = (f32x4){0.f, 0.f, 0.f, 0.f};
#pragma unroll
    for (int mt = 0; mt < 4; ++mt) {
      bf16x8 qh = *(const bf16x8*)&Qh[(mt * 16 + l15) * 32 + 8 * g];
      bf16x8 ql = *(const bf16x8*)&Ql[(mt * 16 + l15) * 32 + 8 * g];
      acc[mt] = MFMA16(qh, kh, acc[mt]);
      acc[mt] = MFMA16(qh, kl, acc[mt]);
      acc[mt] = MFMA16(ql, kh, acc[mt]);
    }
#pragma unroll
    for (int mt = 0; mt < 4; ++mt)
#pragma unroll
      for (int r = 0; r < 4; ++r) {
        short hh, ll;
        split_val(acc[mt][r], hh, ll);
        int xr = mt * 16 + 4 * g + r;
        *(ushort_t*)(AhB + swzb(xr, y * 2)) = (ushort_t)hh;
        *(ushort_t*)(AlB + swzb(xr, y * 2)) = (ushort_t)ll;
      }
  }
  __syncthreads();

  // ===== phase 4: Out = V * A^T, per 16-row c-tile via per-wave swizzled LDS round-trip =====
  {
    char* VhB = smem + OFF_R2 + wv * 4096;   // [16][128B] swz hi
    char* VlB = VhB + 2048;                  // [16][128B] swz lo
    const int cb = 64 * wv;
#pragma unroll
    for (int mt = 0; mt < 4; ++mt) {
#pragma unroll
      for (int nt = 0; nt < 4; ++nt)
#pragma unroll
        for (int r = 0; r < 4; ++r) {
          short hh, ll;
          split_val(vacc[mt][nt][r], hh, ll);
          int colb = (nt * 16 + l15) * 2;
          *(ushort_t*)(VhB + swzb(4 * g + r, colb)) = (ushort_t)hh;
          *(ushort_t*)(VlB + swzb(4 * g + r, colb)) = (ushort_t)ll;
        }
      f32x4 oacc[4];
#pragma unroll
      for (int nt = 0; nt < 4; ++nt) oacc[nt] = (f32x4){0.f, 0.f, 0.f, 0.f};
      __builtin_amdgcn_s_setprio(1);
#pragma unroll
      for (int ys = 0; ys < 2; ++ys) {
        const int yo = ys * 32 + 8 * g;
        bf16x8 vh8 = *(const bf16x8*)(VhB + swzb(l15, yo * 2));
        bf16x8 vl8 = *(const bf16x8*)(VlB + swzb(l15, yo * 2));
#pragma unroll
        for (int nt = 0; nt < 4; ++nt) {
          bf16x8 ah8 = *(const bf16x8*)(AhB + swzb(nt * 16 + l15, yo * 2));
          bf16x8 al8 = *(const bf16x8*)(AlB + swzb(nt * 16 + l15, yo * 2));
          oacc[nt] = MFMA16(vh8, ah8, oacc[nt]);
          oacc[nt] = MFMA16(vh8, al8, oacc[nt]);
          oacc[nt] = MFMA16(vl8, ah8, oacc[nt]);
        }
      }
      __builtin_amdgcn_s_setprio(0);
#pragma unroll
      for (int nt = 0; nt < 4; ++nt)
#pragma unroll
        for (int r = 0; r < 4; ++r)
          out[base + (size_t)(cb + mt * 16 + 4 * g + r) * DHW + nt * 16 + l15] = oacc[nt][r];
    }
  }
}

extern "C" void kernel_launch(void* const* d_in, const int* in_sizes, int n_in,
                              void* d_out, int out_size, void* d_ws, size_t ws_size,
                              hipStream_t stream)
{
  const float* x1 = (const float*)d_in[0];
  const float* x2 = (const float*)d_in[1];
  const float* Wq = (const float*)d_in[2];
  const float* bq = (const float*)d_in[3];
  const float* Wk = (const float*)d_in[4];
  const float* bk = (const float*)d_in[5];
  const float* Wv = (const float*)d_in[6];
  const float* bv = (const float*)d_in[7];
  float* out = (float*)d_out;

  const bool pw = (ws_size >= (size_t)WS_NEED_BYTES) && (d_ws != nullptr);
  if (pw) {
    ushort_t* ws = (ushort_t*)d_ws;
    hipLaunchKernelGGL(prep_w, dim3(320), dim3(256), 0, stream, Wq, Wk, Wv, ws);
    hipLaunchKernelGGL(xattn<true>, dim3(NB * ND * NH), dim3(256), 0, stream,
                       x1, x2, Wq, bq, Wk, bk, Wv, bv, ws, out);
  } else {
    hipLaunchKernelGGL(xattn<false>, dim3(NB * ND * NH), dim3(256), 0, stream,
                       x1, x2, Wq, bq, Wk, bk, Wv, bv, (const ushort_t*)nullptr, out);
  }
}

// Round 5
// 275.383 us; speedup vs baseline: 1.1605x; 1.1605x over previous
//
#include <hip/hip_runtime.h>

// Problem constants
#define NB   2
#define ND   16
#define NH   64
#define DHW  65536       // D*H*W
#define HW   4096        // H*W
#define CDHW 16777216    // C*D*H*W

typedef __attribute__((ext_vector_type(4))) float f32x4;
typedef __attribute__((ext_vector_type(8))) short bf16x8;
typedef unsigned short ushort_t;

#define MFMA16(a, b, c) __builtin_amdgcn_mfma_f32_16x16x32_bf16((a), (b), (c), 0, 0, 0)

// ---------------- ws layout (ushort element offsets) ----------------
#define WS_WQH 0
#define WS_WQL 8192
#define WS_WKH 16384
#define WS_WKL 24576
#define WS_WVH 32768
#define WS_WVL 98304
#define WS_WEIGHT_USHORTS 163840
// QK planes: 4 x [2048 groups][64 x][32 c8]
#define WS_QTH (WS_WEIGHT_USHORTS)
#define WS_QTL (WS_QTH + 4194304)
#define WS_KTH (WS_QTH + 8388608)
#define WS_KTL (WS_QTH + 12582912)
#define WS_FULL_BYTES ((size_t)(WS_WEIGHT_USHORTS + 16777216) * 2)
#define WS_W_BYTES ((size_t)WS_WEIGHT_USHORTS * 2)

__device__ __forceinline__ void split_val(float f, short& h, short& l) {
  unsigned int u = __builtin_bit_cast(unsigned int, f);
  h = (short)(unsigned short)(u >> 16);
  float fh = __builtin_bit_cast(float, u & 0xffff0000u);
  float r = f - fh;
  l = (short)(unsigned short)(__builtin_bit_cast(unsigned int, r) >> 16);
}

__device__ __forceinline__ void load_split8(const float* __restrict__ p, bf16x8& h8, bf16x8& l8) {
  float4 a = *(const float4*)p;
  float4 b = *(const float4*)(p + 4);
  float f[8] = {a.x, a.y, a.z, a.w, b.x, b.y, b.z, b.w};
#pragma unroll
  for (int j = 0; j < 8; ++j) {
    short hh, ll;
    split_val(f[j], hh, ll);
    h8[j] = hh; l8[j] = ll;
  }
}

// byte offset in a [rows][128 B] XOR-swizzled tile (16 B slot granularity)
__device__ __forceinline__ int swzb(int row, int colb) {
  return row * 128 + (((colb) & ~15) ^ ((row & 7) << 4)) + ((colb) & 15);
}

#define GLOAD16(gp, lp) \
  __builtin_amdgcn_global_load_lds((const __attribute__((address_space(1))) void*)(const void*)(gp), \
                                   (__attribute__((address_space(3))) void*)(void*)(lp), 16, 0, 0)

// ---------------- weight pre-split kernel ----------------
__global__ void prep_w(const float* __restrict__ Wq, const float* __restrict__ Wk,
                       const float* __restrict__ Wv, ushort_t* __restrict__ ws) {
  int idx = blockIdx.x * 256 + threadIdx.x;
  const float* src; int off; ushort_t *H, *L;
  if (idx < 8192)       { src = Wq; off = idx;         H = ws + WS_WQH; L = ws + WS_WQL; }
  else if (idx < 16384) { src = Wk; off = idx - 8192;  H = ws + WS_WKH; L = ws + WS_WKL; }
  else if (idx < 81920) { src = Wv; off = idx - 16384; H = ws + WS_WVH; L = ws + WS_WVL; }
  else return;
  short h, l;
  split_val(src[off], h, l);
  H[off] = (ushort_t)h;
  L[off] = (ushort_t)l;
}

// ---------------- kernel A: Q,K projection (per-wave, barrier-free) ----------------
// 2048 blocks x 256 thr; wave task = group x 16-column strip.
__global__ __launch_bounds__(256, 3) void qk_kernel(
    const float* __restrict__ x1, const float* __restrict__ x2,
    const float* __restrict__ bq, const float* __restrict__ bk,
    ushort_t* __restrict__ ws)
{
  __shared__ char asmem[49152];   // 4 waves x ring-3 x [64 ch][16 x] f32 (4096 B)
  const int tid  = threadIdx.x;
  const int lane = tid & 63;
  const int wv   = tid >> 6;
  const int l15  = lane & 15;
  const int g    = lane >> 4;

  const int task  = blockIdx.x * 4 + wv;
  const int grp   = task >> 2;
  const int strip = task & 3;
  const int b   = grp >> 10;
  const int rem = grp & 1023;
  const int d   = rem >> 6;
  const int h   = rem & 63;
  const size_t base = (size_t)b * CDHW + (size_t)d * HW + (size_t)h * 64 + strip * 16;

  const float* x1p = x1 + base;
  const float* x2p = x2 + base;
  char* bufs = asmem + wv * 12288;

  const ushort_t* WqH = ws + WS_WQH;
  const ushort_t* WqL = ws + WS_WQL;
  const ushort_t* WkH = ws + WS_WKH;
  const ushort_t* WkL = ws + WS_WKL;

  // per-lane source offset within a 16-ch x 16-x chunk (lane n -> ch n>>2, x (n&3)*4)
  const size_t loff = (size_t)(lane >> 2) * DHW + (size_t)(lane & 3) * 4;

  f32x4 qacc[2], kacc[2];
#pragma unroll
  for (int mt = 0; mt < 2; ++mt) {
    int r0 = mt * 16 + 4 * g;
    qacc[mt] = (f32x4){bq[r0], bq[r0 + 1], bq[r0 + 2], bq[r0 + 3]};
    kacc[mt] = (f32x4){bk[r0], bk[r0 + 1], bk[r0 + 2], bk[r0 + 3]};
  }

  // stage i (i = 2t + s, s: 0=x1, 1=x2) -> buf (i%3); 4 x global_load_lds(16B)
  auto issue = [&](int i) {
    const int t = i >> 1, s = i & 1;
    const float* src = (s == 0 ? x1p : x2p) + (size_t)t * 64 * DHW;
    char* lb = bufs + (i % 3) * 4096;
#pragma unroll
    for (int k = 0; k < 4; ++k) {
      const float* gp = src + (size_t)(16 * k) * DHW + loff;
      GLOAD16(gp, lb + k * 1024);
    }
  };

  issue(0); issue(1); issue(2);
#pragma unroll
  for (int i = 0; i < 8; ++i) {
    if (i < 6)       asm volatile("s_waitcnt vmcnt(8)" ::: "memory");
    else if (i == 6) asm volatile("s_waitcnt vmcnt(4)" ::: "memory");
    else             asm volatile("s_waitcnt vmcnt(0)" ::: "memory");

    const int t = i >> 1;
    const float* bufF = (const float*)(bufs + (i % 3) * 4096);
    // read + split this stage's fragments (lane l15 = x col, g = k-octet)
    bf16x8 bh[2], bl[2];
#pragma unroll
    for (int ks = 0; ks < 2; ++ks) {
#pragma unroll
      for (int j = 0; j < 8; ++j) {
        float f = bufF[(32 * ks + 8 * g + j) * 16 + l15];
        short hh, ll;
        split_val(f, hh, ll);
        bh[ks][j] = hh; bl[ks][j] = ll;
      }
    }
    asm volatile("s_waitcnt lgkmcnt(0)" ::: "memory");
    if (i + 3 < 8) issue(i + 3);          // refill freed buffer early

    const ushort_t* Wh = (i & 1) ? WkH : WqH;
    const ushort_t* Wl = (i & 1) ? WkL : WqL;
    f32x4* acc = (i & 1) ? kacc : qacc;
#pragma unroll
    for (int ks = 0; ks < 2; ++ks) {
      const int kg = t * 64 + ks * 32 + 8 * g;
#pragma unroll
      for (int mt = 0; mt < 2; ++mt) {
        bf16x8 wh = *(const bf16x8*)&Wh[(size_t)(mt * 16 + l15) * 256 + kg];
        bf16x8 wl = *(const bf16x8*)&Wl[(size_t)(mt * 16 + l15) * 256 + kg];
        acc[mt] = MFMA16(wh, bh[ks], acc[mt]);
        acc[mt] = MFMA16(wh, bl[ks], acc[mt]);
        acc[mt] = MFMA16(wl, bh[ks], acc[mt]);
      }
    }
  }

  // epilogue: split + pack + store QT/KT [x][c8]
  ushort_t* QTh = ws + WS_QTH + grp * 2048;
  ushort_t* QTl = ws + WS_QTL + grp * 2048;
  ushort_t* KTh = ws + WS_KTH + grp * 2048;
  ushort_t* KTl = ws + WS_KTL + grp * 2048;
  const int xrow = strip * 16 + l15;
#pragma unroll
  for (int mt = 0; mt < 2; ++mt) {
    unsigned int h01 = 0, h23 = 0, l01 = 0, l23 = 0;
    short hh, ll;
    split_val(qacc[mt][0], hh, ll); h01 = (ushort_t)hh;            l01 = (ushort_t)ll;
    split_val(qacc[mt][1], hh, ll); h01 |= ((unsigned)(ushort_t)hh) << 16; l01 |= ((unsigned)(ushort_t)ll) << 16;
    split_val(qacc[mt][2], hh, ll); h23 = (ushort_t)hh;            l23 = (ushort_t)ll;
    split_val(qacc[mt][3], hh, ll); h23 |= ((unsigned)(ushort_t)hh) << 16; l23 |= ((unsigned)(ushort_t)ll) << 16;
    int off = xrow * 32 + mt * 16 + 4 * g;
    uint2 vh; vh.x = h01; vh.y = h23;
    uint2 vl; vl.x = l01; vl.y = l23;
    *(uint2*)&QTh[off] = vh;
    *(uint2*)&QTl[off] = vl;
    split_val(kacc[mt][0], hh, ll); h01 = (ushort_t)hh;            l01 = (ushort_t)ll;
    split_val(kacc[mt][1], hh, ll); h01 |= ((unsigned)(ushort_t)hh) << 16; l01 |= ((unsigned)(ushort_t)ll) << 16;
    split_val(kacc[mt][2], hh, ll); h23 = (ushort_t)hh;            l23 = (ushort_t)ll;
    split_val(kacc[mt][3], hh, ll); h23 |= ((unsigned)(ushort_t)hh) << 16; l23 |= ((unsigned)(ushort_t)ll) << 16;
    vh.x = h01; vh.y = h23;
    vl.x = l01; vl.y = l23;
    *(uint2*)&KTh[off] = vh;
    *(uint2*)&KTl[off] = vl;
  }
}

// ---------------- kernel B: V + attention ----------------
// 4096 blocks = (group, channel-half). LDS: Xth/Xtl|Vb 16K + Ah/Al 16K + Xlin 16K
#define B_OFF_XTH 0
#define B_OFF_XTL 8192
#define B_OFF_AH  16384
#define B_OFF_AL  24576
#define B_OFF_XLIN 32768
#define B_SMEM 49152

__global__ __launch_bounds__(256, 3) void xattn_v(
    const float* __restrict__ x2, const float* __restrict__ bv,
    const ushort_t* __restrict__ wsp, float* __restrict__ out)
{
  __shared__ char smem[B_SMEM];
  char*  XthB = smem + B_OFF_XTH;
  char*  XtlB = smem + B_OFF_XTL;
  char*  AhB  = smem + B_OFF_AH;
  char*  AlB  = smem + B_OFF_AL;
  float* Xlin = (float*)(smem + B_OFF_XLIN);   // [64][64] f32, pad-free

  const int tid  = threadIdx.x;
  const int lane = tid & 63;
  const int wv   = tid >> 6;
  const int l15  = lane & 15;
  const int g    = lane >> 4;

  const int bid   = blockIdx.x;
  const int grp   = bid >> 1;
  const int chalf = bid & 1;
  const int cbase = chalf * 128;
  const int b   = grp >> 10;
  const int rem = grp & 1023;
  const int d   = rem >> 6;
  const int h   = rem & 63;
  const size_t base = (size_t)b * CDHW + (size_t)d * HW + (size_t)h * 64;
  const float* x2p = x2 + base;

  const ushort_t* WvH = wsp + WS_WVH;
  const ushort_t* WvL = wsp + WS_WVL;

  // staging registers (4 x float4 per wave = wave's 16 channels of the tile)
  float4 pf[4];
  auto issue_pf = [&](const float* __restrict__ src) {
#pragma unroll
    for (int i = 0; i < 4; ++i) {
      int ch = 16 * wv + g + 4 * i;
      pf[i] = *(const float4*)(src + (size_t)ch * DHW + 4 * l15);
    }
  };
  auto write_xlin = [&]() {
#pragma unroll
    for (int i = 0; i < 4; ++i) {
      int ch = 16 * wv + g + 4 * i;
      *(float4*)&Xlin[ch * 64 + 4 * l15] = pf[i];
    }
  };
  auto passB = [&]() {
#pragma unroll
    for (int bb = 0; bb < 2; ++bb) {
      int c0 = 16 * wv + 8 * bb;
      bf16x8 h8, l8;
#pragma unroll
      for (int j = 0; j < 8; ++j) {
        float f = Xlin[(c0 + j) * 64 + lane];
        short hh, ll;
        split_val(f, hh, ll);
        h8[j] = hh; l8[j] = ll;
      }
      *(bf16x8*)(XthB + swzb(lane, c0 * 2)) = h8;
      *(bf16x8*)(XtlB + swzb(lane, c0 * 2)) = l8;
    }
  };
  auto ldsx = [&](const char* B, int row, int ko) -> bf16x8 {
    return *(const bf16x8*)(B + swzb(row, ko * 2));
  };

  // V accumulators: wave's 32 channels = rows [cbase+32wv, +32)
  f32x4 vacc[2][4];
#pragma unroll
  for (int mt = 0; mt < 2; ++mt) {
    int r0 = cbase + 32 * wv + mt * 16 + 4 * g;
    f32x4 bb = (f32x4){bv[r0], bv[r0 + 1], bv[r0 + 2], bv[r0 + 3]};
#pragma unroll
    for (int nt = 0; nt < 4; ++nt) vacc[mt][nt] = bb;
  }

  // ===== prologue: prefetch tile0; A = Q^T K from ws (hides prefetch latency) =====
  issue_pf(x2p);
  {
    const ushort_t* QTh = wsp + WS_QTH + grp * 2048;
    const ushort_t* QTl = wsp + WS_QTL + grp * 2048;
    const ushort_t* KTh = wsp + WS_KTH + grp * 2048;
    const ushort_t* KTl = wsp + WS_KTL + grp * 2048;
    const int y = 16 * wv + l15;
    bf16x8 kh = *(const bf16x8*)&KTh[y * 32 + 8 * g];
    bf16x8 kl = *(const bf16x8*)&KTl[y * 32 + 8 * g];
    f32x4 acc[4];
#pragma unroll
    for (int mt = 0; mt < 4; ++mt) acc[mt] = (f32x4){0.f, 0.f, 0.f, 0.f};
#pragma unroll
    for (int mt = 0; mt < 4; ++mt) {
      bf16x8 qh = *(const bf16x8*)&QTh[(mt * 16 + l15) * 32 + 8 * g];
      bf16x8 ql = *(const bf16x8*)&QTl[(mt * 16 + l15) * 32 + 8 * g];
      acc[mt] = MFMA16(qh, kh, acc[mt]);
      acc[mt] = MFMA16(qh, kl, acc[mt]);
      acc[mt] = MFMA16(ql, kh, acc[mt]);
    }
#pragma unroll
    for (int mt = 0; mt < 4; ++mt)
#pragma unroll
      for (int r = 0; r < 4; ++r) {
        short hh, ll;
        split_val(acc[mt][r], hh, ll);
        int xr = mt * 16 + 4 * g + r;
        *(ushort_t*)(AhB + swzb(xr, y * 2)) = (ushort_t)hh;
        *(ushort_t*)(AlB + swzb(xr, y * 2)) = (ushort_t)ll;
      }
  }
  write_xlin();
  __syncthreads();

  // ===== V loop: 4 c-tiles of x2, 2 barriers per tile =====
  for (int t = 0; t < 4; ++t) {
    passB();
    __syncthreads();                       // Xth(t) visible; Xlin(t) free
    if (t < 3) issue_pf(x2p + (size_t)(t + 1) * 64 * DHW);
#pragma unroll
    for (int ks = 0; ks < 2; ++ks) {
      const int ko = ks * 32 + 8 * g;
      const int kg = t * 64 + ko;
      bf16x8 xh[4], xl[4];
#pragma unroll
      for (int nt = 0; nt < 4; ++nt) {
        xh[nt] = ldsx(XthB, nt * 16 + l15, ko);
        xl[nt] = ldsx(XtlB, nt * 16 + l15, ko);
      }
      __builtin_amdgcn_s_setprio(1);
#pragma unroll
      for (int mt = 0; mt < 2; ++mt) {
        bf16x8 wh = *(const bf16x8*)&WvH[(size_t)(cbase + 32 * wv + mt * 16 + l15) * 256 + kg];
        bf16x8 wl = *(const bf16x8*)&WvL[(size_t)(cbase + 32 * wv + mt * 16 + l15) * 256 + kg];
#pragma unroll
        for (int nt = 0; nt < 4; ++nt) {
          vacc[mt][nt] = MFMA16(wh, xh[nt], vacc[mt][nt]);
          vacc[mt][nt] = MFMA16(wh, xl[nt], vacc[mt][nt]);
          vacc[mt][nt] = MFMA16(wl, xh[nt], vacc[mt][nt]);
        }
      }
      __builtin_amdgcn_s_setprio(0);
    }
    if (t < 3) write_xlin();               // next tile -> Xlin
    __syncthreads();                       // Xlin(t+1) visible; Xth(t) free
  }

  // ===== phase 4: Out = V * A^T; Vb overlays Xth region (dead) =====
  {
    char* VhB = smem + B_OFF_XTH + wv * 4096;
    char* VlB = VhB + 2048;
#pragma unroll
    for (int mt = 0; mt < 2; ++mt) {
#pragma unroll
      for (int nt = 0; nt < 4; ++nt)
#pragma unroll
        for (int r = 0; r < 4; ++r) {
          short hh, ll;
          split_val(vacc[mt][nt][r], hh, ll);
          int colb = (nt * 16 + l15) * 2;
          *(ushort_t*)(VhB + swzb(4 * g + r, colb)) = (ushort_t)hh;
          *(ushort_t*)(VlB + swzb(4 * g + r, colb)) = (ushort_t)ll;
        }
      f32x4 oacc[4];
#pragma unroll
      for (int nt = 0; nt < 4; ++nt) oacc[nt] = (f32x4){0.f, 0.f, 0.f, 0.f};
      __builtin_amdgcn_s_setprio(1);
#pragma unroll
      for (int ys = 0; ys < 2; ++ys) {
        const int yo = ys * 32 + 8 * g;
        bf16x8 vh8 = *(const bf16x8*)(VhB + swzb(l15, yo * 2));
        bf16x8 vl8 = *(const bf16x8*)(VlB + swzb(l15, yo * 2));
#pragma unroll
        for (int nt = 0; nt < 4; ++nt) {
          bf16x8 ah8 = *(const bf16x8*)(AhB + swzb(nt * 16 + l15, yo * 2));
          bf16x8 al8 = *(const bf16x8*)(AlB + swzb(nt * 16 + l15, yo * 2));
          oacc[nt] = MFMA16(vh8, ah8, oacc[nt]);
          oacc[nt] = MFMA16(vh8, al8, oacc[nt]);
          oacc[nt] = MFMA16(vl8, ah8, oacc[nt]);
        }
      }
      __builtin_amdgcn_s_setprio(0);
#pragma unroll
      for (int nt = 0; nt < 4; ++nt)
#pragma unroll
        for (int r = 0; r < 4; ++r)
          out[base + (size_t)(cbase + 32 * wv + mt * 16 + 4 * g + r) * DHW + nt * 16 + l15] = oacc[nt][r];
    }
  }
}

// ---------------- fused fallback (r2 kernel, 207 us, proven) ----------------
#define XT_LD 72
#define QK_LD 40
#define A_LD  72
#define VB_LD 72
#define OFF_XTH 0
#define OFF_XTL 9216
#define OFF_R2  18432
#define OFF_KH  18432
#define OFF_KL  23552
#define OFF_AH  0
#define OFF_AL  9216
#define OFF_QH  36864
#define OFF_QL  41984
#define SMEM_BYTES 47104

template<bool PW>
__global__ __launch_bounds__(256, 3) void xattn_fused(
    const float* __restrict__ x1, const float* __restrict__ x2,
    const float* __restrict__ Wq, const float* __restrict__ bq,
    const float* __restrict__ Wk, const float* __restrict__ bk,
    const float* __restrict__ Wv, const float* __restrict__ bv,
    const ushort_t* __restrict__ wsp, float* __restrict__ out)
{
  __shared__ char smem[SMEM_BYTES];
  ushort_t* Xth  = (ushort_t*)(smem + OFF_XTH);
  ushort_t* Xtl  = (ushort_t*)(smem + OFF_XTL);
  float*    Xlin = (float*)(smem + OFF_R2);
  ushort_t* Kh   = (ushort_t*)(smem + OFF_KH);
  ushort_t* Kl   = (ushort_t*)(smem + OFF_KL);
  ushort_t* Vb   = (ushort_t*)(smem + OFF_R2);
  ushort_t* Ah   = (ushort_t*)(smem + OFF_AH);
  ushort_t* Al   = (ushort_t*)(smem + OFF_AL);
  ushort_t* Qh   = (ushort_t*)(smem + OFF_QH);
  ushort_t* Ql   = (ushort_t*)(smem + OFF_QL);

  const int tid  = threadIdx.x;
  const int lane = tid & 63;
  const int wv   = tid >> 6;
  const int l15  = lane & 15;
  const int g    = lane >> 4;

  const int grp = blockIdx.x;
  const int b   = grp >> 10;
  const int rem = grp & 1023;
  const int d   = rem >> 6;
  const int h   = rem & 63;
  const size_t base = (size_t)b * CDHW + (size_t)d * HW + (size_t)h * 64;

  const ushort_t* WqH = wsp + WS_WQH;
  const ushort_t* WqL = wsp + WS_WQL;
  const ushort_t* WkH = wsp + WS_WKH;
  const ushort_t* WkL = wsp + WS_WKL;
  const ushort_t* WvH = wsp + WS_WVH;
  const ushort_t* WvL = wsp + WS_WVL;

  auto passA = [&](const float* __restrict__ src) {
#pragma unroll
    for (int i = 0; i < 4; ++i) {
      int ch = 16 * wv + (lane >> 4) + 4 * i;
      int c4 = (lane & 15) << 2;
      float4 v = *(const float4*)(src + (size_t)ch * DHW + c4);
      *(float4*)&Xlin[ch * 66 + c4] = v;
    }
  };
  auto passB = [&]() {
#pragma unroll
    for (int bb = 0; bb < 2; ++bb) {
      int c0 = 16 * wv + 8 * bb;
      bf16x8 h8, l8;
#pragma unroll
      for (int j = 0; j < 8; ++j) {
        float f = Xlin[(c0 + j) * 66 + lane];
        short hh, ll;
        split_val(f, hh, ll);
        h8[j] = hh; l8[j] = ll;
      }
      *(bf16x8*)&Xth[lane * XT_LD + c0] = h8;
      *(bf16x8*)&Xtl[lane * XT_LD + c0] = l8;
    }
  };

  {
    f32x4 qacc[2];
#pragma unroll
    for (int mt = 0; mt < 2; ++mt) {
      int r0 = mt * 16 + 4 * g;
      qacc[mt] = (f32x4){bq[r0], bq[r0 + 1], bq[r0 + 2], bq[r0 + 3]};
    }
    const float* x1p = x1 + base;
    for (int t = 0; t < 4; ++t) {
      passA(x1p + (size_t)t * 64 * DHW);
      __syncthreads();
      passB();
      __syncthreads();
#pragma unroll
      for (int ks = 0; ks < 2; ++ks) {
        const int ko = ks * 32 + 8 * g;
        const int kg = t * 64 + ko;
        bf16x8 bh = *(const bf16x8*)&Xth[(16 * wv + l15) * XT_LD + ko];
        bf16x8 bl = *(const bf16x8*)&Xtl[(16 * wv + l15) * XT_LD + ko];
#pragma unroll
        for (int mt = 0; mt < 2; ++mt) {
          bf16x8 wh, wl;
          if constexpr (PW) {
            wh = *(const bf16x8*)&WqH[(size_t)(mt * 16 + l15) * 256 + kg];
            wl = *(const bf16x8*)&WqL[(size_t)(mt * 16 + l15) * 256 + kg];
          } else {
            load_split8(Wq + (size_t)(mt * 16 + l15) * 256 + kg, wh, wl);
          }
          qacc[mt] = MFMA16(wh, bh, qacc[mt]);
          qacc[mt] = MFMA16(wh, bl, qacc[mt]);
          qacc[mt] = MFMA16(wl, bh, qacc[mt]);
        }
      }
      __syncthreads();
    }
    const int x = 16 * wv + l15;
#pragma unroll
    for (int mt = 0; mt < 2; ++mt)
#pragma unroll
      for (int r = 0; r < 4; ++r) {
        short hh, ll;
        split_val(qacc[mt][r], hh, ll);
        Qh[x * QK_LD + mt * 16 + 4 * g + r] = (ushort_t)hh;
        Ql[x * QK_LD + mt * 16 + 4 * g + r] = (ushort_t)ll;
      }
  }

  f32x4 vacc[4][4];
  {
    f32x4 kacc[2];
#pragma unroll
    for (int mt = 0; mt < 2; ++mt) {
      int r0 = mt * 16 + 4 * g;
      kacc[mt] = (f32x4){bk[r0], bk[r0 + 1], bk[r0 + 2], bk[r0 + 3]};
    }
#pragma unroll
    for (int mt = 0; mt < 4; ++mt) {
      int r0 = 64 * wv + mt * 16 + 4 * g;
      f32x4 bb = (f32x4){bv[r0], bv[r0 + 1], bv[r0 + 2], bv[r0 + 3]};
#pragma unroll
      for (int nt = 0; nt < 4; ++nt) vacc[mt][nt] = bb;
    }
    const float* x2p = x2 + base;
    for (int t = 0; t < 4; ++t) {
      passA(x2p + (size_t)t * 64 * DHW);
      __syncthreads();
      passB();
      __syncthreads();
#pragma unroll
      for (int ks = 0; ks < 2; ++ks) {
        const int ko = ks * 32 + 8 * g;
        const int kg = t * 64 + ko;
        bf16x8 xh[4], xl[4];
#pragma unroll
        for (int nt = 0; nt < 4; ++nt) {
          xh[nt] = *(const bf16x8*)&Xth[(nt * 16 + l15) * XT_LD + ko];
          xl[nt] = *(const bf16x8*)&Xtl[(nt * 16 + l15) * XT_LD + ko];
        }
        {
          bf16x8 bh = *(const bf16x8*)&Xth[(16 * wv + l15) * XT_LD + ko];
          bf16x8 bl = *(const bf16x8*)&Xtl[(16 * wv + l15) * XT_LD + ko];
#pragma unroll
          for (int mt = 0; mt < 2; ++mt) {
            bf16x8 wh, wl;
            if constexpr (PW) {
              wh = *(const bf16x8*)&WkH[(size_t)(mt * 16 + l15) * 256 + kg];
              wl = *(const bf16x8*)&WkL[(size_t)(mt * 16 + l15) * 256 + kg];
            } else {
              load_split8(Wk + (size_t)(mt * 16 + l15) * 256 + kg, wh, wl);
            }
            kacc[mt] = MFMA16(wh, bh, kacc[mt]);
            kacc[mt] = MFMA16(wh, bl, kacc[mt]);
            kacc[mt] = MFMA16(wl, bh, kacc[mt]);
          }
        }
#pragma unroll
        for (int mt = 0; mt < 4; ++mt) {
          bf16x8 wh, wl;
          if constexpr (PW) {
            wh = *(const bf16x8*)&WvH[(size_t)(64 * wv + mt * 16 + l15) * 256 + kg];
            wl = *(const bf16x8*)&WvL[(size_t)(64 * wv + mt * 16 + l15) * 256 + kg];
          } else {
            load_split8(Wv + (size_t)(64 * wv + mt * 16 + l15) * 256 + kg, wh, wl);
          }
#pragma unroll
          for (int nt = 0; nt < 4; ++nt) {
            vacc[mt][nt] = MFMA16(wh, xh[nt], vacc[mt][nt]);
            vacc[mt][nt] = MFMA16(wh, xl[nt], vacc[mt][nt]);
            vacc[mt][nt] = MFMA16(wl, xh[nt], vacc[mt][nt]);
          }
        }
      }
      __syncthreads();
    }
    const int y = 16 * wv + l15;
#pragma unroll
    for (int mt = 0; mt < 2; ++mt)
#pragma unroll
      for (int r = 0; r < 4; ++r) {
        short hh, ll;
        split_val(kacc[mt][r], hh, ll);
        Kh[y * QK_LD + mt * 16 + 4 * g + r] = (ushort_t)hh;
        Kl[y * QK_LD + mt * 16 + 4 * g + r] = (ushort_t)ll;
      }
  }
  __syncthreads();

  {
    const int y = 16 * wv + l15;
    bf16x8 kh = *(const bf16x8*)&Kh[y * QK_LD + 8 * g];
    bf16x8 kl = *(const bf16x8*)&Kl[y * QK_LD + 8 * g];
    f32x4 acc[4];
#pragma unroll
    for (int mt = 0; mt < 4; ++mt) acc[mt] = (f32x4){0.f, 0.f, 0.f, 0.f};
#pragma unroll
    for (int mt = 0; mt < 4; ++mt) {
      bf16x8 qh = *(const bf16x8*)&Qh[(mt * 16 + l15) * QK_LD + 8 * g];
      bf16x8 ql = *(const bf16x8*)&Ql[(mt * 16 + l15) * QK_LD + 8 * g];
      acc[mt] = MFMA16(qh, kh, acc[mt]);
      acc[mt] = MFMA16(qh, kl, acc[mt]);
      acc[mt] = MFMA16(ql, kh, acc[mt]);
    }
#pragma unroll
    for (int mt = 0; mt < 4; ++mt)
#pragma unroll
      for (int r = 0; r < 4; ++r) {
        short hh, ll;
        split_val(acc[mt][r], hh, ll);
        Ah[(mt * 16 + 4 * g + r) * A_LD + y] = (ushort_t)hh;
        Al[(mt * 16 + 4 * g + r) * A_LD + y] = (ushort_t)ll;
      }
  }
  __syncthreads();

  {
    ushort_t* Vh = Vb + wv * 2304;
    ushort_t* Vl = Vh + 1152;
    const int cb = 64 * wv;
#pragma unroll
    for (int mt = 0; mt < 4; ++mt) {
#pragma unroll
      for (int nt = 0; nt < 4; ++nt)
#pragma unroll
        for (int r = 0; r < 4; ++r) {
          short hh, ll;
          split_val(vacc[mt][nt][r], hh, ll);
          Vh[(4 * g + r) * VB_LD + nt * 16 + l15] = (ushort_t)hh;
          Vl[(4 * g + r) * VB_LD + nt * 16 + l15] = (ushort_t)ll;
        }
      f32x4 oacc[4];
#pragma unroll
      for (int nt = 0; nt < 4; ++nt) oacc[nt] = (f32x4){0.f, 0.f, 0.f, 0.f};
#pragma unroll
      for (int ys = 0; ys < 2; ++ys) {
        const int yo = ys * 32 + 8 * g;
        bf16x8 vh8 = *(const bf16x8*)&Vh[l15 * VB_LD + yo];
        bf16x8 vl8 = *(const bf16x8*)&Vl[l15 * VB_LD + yo];
#pragma unroll
        for (int nt = 0; nt < 4; ++nt) {
          bf16x8 ah8 = *(const bf16x8*)&Ah[(nt * 16 + l15) * A_LD + yo];
          bf16x8 al8 = *(const bf16x8*)&Al[(nt * 16 + l15) * A_LD + yo];
          oacc[nt] = MFMA16(vh8, ah8, oacc[nt]);
          oacc[nt] = MFMA16(vh8, al8, oacc[nt]);
          oacc[nt] = MFMA16(vl8, ah8, oacc[nt]);
        }
      }
#pragma unroll
      for (int nt = 0; nt < 4; ++nt)
#pragma unroll
        for (int r = 0; r < 4; ++r)
          out[base + (size_t)(cb + mt * 16 + 4 * g + r) * DHW + nt * 16 + l15] = oacc[nt][r];
    }
  }
}

extern "C" void kernel_launch(void* const* d_in, const int* in_sizes, int n_in,
                              void* d_out, int out_size, void* d_ws, size_t ws_size,
                              hipStream_t stream)
{
  const float* x1 = (const float*)d_in[0];
  const float* x2 = (const float*)d_in[1];
  const float* Wq = (const float*)d_in[2];
  const float* bq = (const float*)d_in[3];
  const float* Wk = (const float*)d_in[4];
  const float* bk = (const float*)d_in[5];
  const float* Wv = (const float*)d_in[6];
  const float* bv = (const float*)d_in[7];
  float* out = (float*)d_out;

  if (d_ws && ws_size >= WS_FULL_BYTES) {
    ushort_t* ws = (ushort_t*)d_ws;
    hipLaunchKernelGGL(prep_w, dim3(320), dim3(256), 0, stream, Wq, Wk, Wv, ws);
    hipLaunchKernelGGL(qk_kernel, dim3(2048), dim3(256), 0, stream, x1, x2, bq, bk, ws);
    hipLaunchKernelGGL(xattn_v, dim3(4096), dim3(256), 0, stream, x2, bv, ws, out);
  } else if (d_ws && ws_size >= WS_W_BYTES) {
    ushort_t* ws = (ushort_t*)d_ws;
    hipLaunchKernelGGL(prep_w, dim3(320), dim3(256), 0, stream, Wq, Wk, Wv, ws);
    hipLaunchKernelGGL(xattn_fused<true>, dim3(2048), dim3(256), 0, stream,
                       x1, x2, Wq, bq, Wk, bk, Wv, bv, ws, out);
  } else {
    hipLaunchKernelGGL(xattn_fused<false>, dim3(2048), dim3(256), 0, stream,
                       x1, x2, Wq, bq, Wk, bk, Wv, bv, (const ushort_t*)nullptr, out);
  }
}

// Round 6
// 226.235 us; speedup vs baseline: 1.4126x; 1.2172x over previous
//
#include <hip/hip_runtime.h>

// Problem constants
#define NB   2
#define ND   16
#define NH   64
#define DHW  65536       // D*H*W
#define HW   4096        // H*W
#define CDHW 16777216    // C*D*H*W

typedef __attribute__((ext_vector_type(4))) float f32x4;
typedef __attribute__((ext_vector_type(8))) short bf16x8;
typedef unsigned short ushort_t;

#define MFMA16(a, b, c) __builtin_amdgcn_mfma_f32_16x16x32_bf16((a), (b), (c), 0, 0, 0)

// ---------------- LDS layout (bytes), total 49152 -> 3 blocks/CU ----------------
// R1 [0,16384):      Xth[64][128B] swz + Xtl[64][128B] swz   ->  Ah/Al (same layout)
// R2 [16384,32768):  Xlin[64][64] f32 (pad-free)             ->  Vb 4 waves x 4096 B
// R3 [32768,49152):  Qh/Ql/Kh/Kl [64][32] ushort (4 KB each)
#define OFF_XTH 0
#define OFF_XTL 8192
#define OFF_AH  0
#define OFF_AL  8192
#define OFF_R2  16384
#define OFF_QH  32768
#define OFF_QL  36864
#define OFF_KH  40960
#define OFF_KL  45056
#define SMEM_BYTES 49152

// ---------------- ws layout (ushort element offsets) ----------------
#define WS_WQH 0
#define WS_WQL 8192
#define WS_WKH 16384
#define WS_WKL 24576
#define WS_WVH 32768
#define WS_WVL 98304
#define WS_W_BYTES ((size_t)163840 * 2)

__device__ __forceinline__ void split_val(float f, short& h, short& l) {
  unsigned int u = __builtin_bit_cast(unsigned int, f);
  h = (short)(unsigned short)(u >> 16);
  float fh = __builtin_bit_cast(float, u & 0xffff0000u);
  float r = f - fh;
  l = (short)(unsigned short)(__builtin_bit_cast(unsigned int, r) >> 16);
}

__device__ __forceinline__ void load_split8(const float* __restrict__ p, bf16x8& h8, bf16x8& l8) {
  float4 a = *(const float4*)p;
  float4 b = *(const float4*)(p + 4);
  float f[8] = {a.x, a.y, a.z, a.w, b.x, b.y, b.z, b.w};
#pragma unroll
  for (int j = 0; j < 8; ++j) {
    short hh, ll;
    split_val(f[j], hh, ll);
    h8[j] = hh; l8[j] = ll;
  }
}

// byte offset in a [rows][128 B] XOR-swizzled tile (16 B slot granularity)
__device__ __forceinline__ int swzb(int row, int colb) {
  return row * 128 + (((colb) & ~15) ^ ((row & 7) << 4)) + ((colb) & 15);
}

// ---------------- weight pre-split kernel ----------------
__global__ void prep_w(const float* __restrict__ Wq, const float* __restrict__ Wk,
                       const float* __restrict__ Wv, ushort_t* __restrict__ ws) {
  int idx = blockIdx.x * 256 + threadIdx.x;
  const float* src; int off; ushort_t *H, *L;
  if (idx < 8192)       { src = Wq; off = idx;         H = ws + WS_WQH; L = ws + WS_WQL; }
  else if (idx < 16384) { src = Wk; off = idx - 8192;  H = ws + WS_WKH; L = ws + WS_WKL; }
  else if (idx < 81920) { src = Wv; off = idx - 16384; H = ws + WS_WVH; L = ws + WS_WVL; }
  else return;
  short h, l;
  split_val(src[off], h, l);
  H[off] = (ushort_t)h;
  L[off] = (ushort_t)l;
}

// ---------------- main fused kernel ----------------
template<bool PW>
__global__ __launch_bounds__(256, 3) void xattn_fused(
    const float* __restrict__ x1, const float* __restrict__ x2,
    const float* __restrict__ Wq, const float* __restrict__ bq,
    const float* __restrict__ Wk, const float* __restrict__ bk,
    const float* __restrict__ Wv, const float* __restrict__ bv,
    const ushort_t* __restrict__ wsp, float* __restrict__ out)
{
  __shared__ char smem[SMEM_BYTES];
  char*     XthB = smem + OFF_XTH;               // [64][128B] swz (col = ch*2)
  char*     XtlB = smem + OFF_XTL;
  char*     AhB  = smem + OFF_AH;                // overlays Xth after staging done
  char*     AlB  = smem + OFF_AL;
  float*    Xlin = (float*)(smem + OFF_R2);      // [64][64] f32 (pad-free; 0 conflicts proven)
  ushort_t* Qh   = (ushort_t*)(smem + OFF_QH);   // [64][32]
  ushort_t* Ql   = (ushort_t*)(smem + OFF_QL);
  ushort_t* Kh   = (ushort_t*)(smem + OFF_KH);
  ushort_t* Kl   = (ushort_t*)(smem + OFF_KL);

  const int tid  = threadIdx.x;
  const int lane = tid & 63;
  const int wv   = tid >> 6;
  const int l15  = lane & 15;
  const int g    = lane >> 4;

  // XCD-aware swizzle: 2048 blocks, 8 XCDs -> 256 consecutive groups per XCD
  const int bid = blockIdx.x;
  const int grp = (bid & 7) * 256 + (bid >> 3);
  const int b   = grp >> 10;
  const int rem = grp & 1023;
  const int d   = rem >> 6;
  const int h   = rem & 63;
  const size_t base = (size_t)b * CDHW + (size_t)d * HW + (size_t)h * 64;

  const ushort_t* WqH = wsp + WS_WQH;
  const ushort_t* WqL = wsp + WS_WQL;
  const ushort_t* WkH = wsp + WS_WKH;
  const ushort_t* WkL = wsp + WS_WKL;
  const ushort_t* WvH = wsp + WS_WVH;
  const ushort_t* WvL = wsp + WS_WVL;

  const float* x1p = x1 + base;
  const float* x2p = x2 + base;

  // staging registers: 4 x float4 per thread (wave's 16 channels, 256B/channel coalesced)
  float4 pf[4];
  auto issue_pf = [&](const float* __restrict__ src) {
#pragma unroll
    for (int i = 0; i < 4; ++i) {
      int ch = 16 * wv + g + 4 * i;
      pf[i] = *(const float4*)(src + (size_t)ch * DHW + 4 * l15);
    }
  };
  auto write_xlin = [&]() {
#pragma unroll
    for (int i = 0; i < 4; ++i) {
      int ch = 16 * wv + g + 4 * i;
      *(float4*)&Xlin[ch * 64 + 4 * l15] = pf[i];
    }
  };
  // transpose + split the wave's 16 channels into swizzled Xth/Xtl (row = lane = x)
  auto passB = [&]() {
#pragma unroll
    for (int bb = 0; bb < 2; ++bb) {
      int c0 = 16 * wv + 8 * bb;
      bf16x8 h8, l8;
#pragma unroll
      for (int j = 0; j < 8; ++j) {
        float f = Xlin[(c0 + j) * 64 + lane];
        short hh, ll;
        split_val(f, hh, ll);
        h8[j] = hh; l8[j] = ll;
      }
      *(bf16x8*)(XthB + swzb(lane, c0 * 2)) = h8;
      *(bf16x8*)(XtlB + swzb(lane, c0 * 2)) = l8;
    }
  };
  auto ldsx = [&](const char* B, int row, int ko) -> bf16x8 {
    return *(const bf16x8*)(B + swzb(row, ko * 2));
  };

  // ===== x1 half: stream 4 c-tiles, accumulate Q^T (wave's x-quarter) =====
  {
    f32x4 qacc[2];
#pragma unroll
    for (int mt = 0; mt < 2; ++mt) {
      int r0 = mt * 16 + 4 * g;
      qacc[mt] = (f32x4){bq[r0], bq[r0 + 1], bq[r0 + 2], bq[r0 + 3]};
    }
    issue_pf(x1p);
    write_xlin();
    __syncthreads();                       // Xlin(t0) visible
#pragma unroll
    for (int t = 0; t < 4; ++t) {
      issue_pf(t < 3 ? x1p + (size_t)(t + 1) * 64 * DHW : x2p);  // full-tile-ahead prefetch
      passB();
      __syncthreads();                     // Xth(t) visible; Xlin(t) free
#pragma unroll
      for (int ks = 0; ks < 2; ++ks) {
        const int ko = ks * 32 + 8 * g;
        const int kg = t * 64 + ko;
        bf16x8 bh = ldsx(XthB, 16 * wv + l15, ko);
        bf16x8 bl = ldsx(XtlB, 16 * wv + l15, ko);
#pragma unroll
        for (int mt = 0; mt < 2; ++mt) {
          bf16x8 wh, wl;
          if constexpr (PW) {
            wh = *(const bf16x8*)&WqH[(size_t)(mt * 16 + l15) * 256 + kg];
            wl = *(const bf16x8*)&WqL[(size_t)(mt * 16 + l15) * 256 + kg];
          } else {
            load_split8(Wq + (size_t)(mt * 16 + l15) * 256 + kg, wh, wl);
          }
          qacc[mt] = MFMA16(wh, bh, qacc[mt]);
          qacc[mt] = MFMA16(wh, bl, qacc[mt]);
          qacc[mt] = MFMA16(wl, bh, qacc[mt]);
        }
      }
      if (t == 3) {
        // write Q split to R3 (untouched by staging)
        const int x = 16 * wv + l15;
#pragma unroll
        for (int mt = 0; mt < 2; ++mt)
#pragma unroll
          for (int r = 0; r < 4; ++r) {
            short hh, ll;
            split_val(qacc[mt][r], hh, ll);
            Qh[x * 32 + mt * 16 + 4 * g + r] = (ushort_t)hh;
            Ql[x * 32 + mt * 16 + 4 * g + r] = (ushort_t)ll;
          }
      }
      write_xlin();                        // tile t+1 (or x2 t0) -> Xlin
      __syncthreads();
    }
  }

  // ===== x2 half: stream 4 c-tiles, accumulate K^T + V =====
  f32x4 vacc[4][4];
  {
    f32x4 kacc[2];
#pragma unroll
    for (int mt = 0; mt < 2; ++mt) {
      int r0 = mt * 16 + 4 * g;
      kacc[mt] = (f32x4){bk[r0], bk[r0 + 1], bk[r0 + 2], bk[r0 + 3]};
    }
#pragma unroll
    for (int mt = 0; mt < 4; ++mt) {
      int r0 = 64 * wv + mt * 16 + 4 * g;
      f32x4 bb = (f32x4){bv[r0], bv[r0 + 1], bv[r0 + 2], bv[r0 + 3]};
#pragma unroll
      for (int nt = 0; nt < 4; ++nt) vacc[mt][nt] = bb;
    }
#pragma unroll
    for (int t = 0; t < 4; ++t) {
      if (t < 3) issue_pf(x2p + (size_t)(t + 1) * 64 * DHW);
      passB();
      __syncthreads();
#pragma unroll
      for (int ks = 0; ks < 2; ++ks) {
        const int ko = ks * 32 + 8 * g;
        const int kg = t * 64 + ko;
        bf16x8 xh[4], xl[4];
#pragma unroll
        for (int nt = 0; nt < 4; ++nt) {
          xh[nt] = ldsx(XthB, nt * 16 + l15, ko);
          xl[nt] = ldsx(XtlB, nt * 16 + l15, ko);
        }
        // K (B-frag re-loaded explicitly: no runtime-indexed reg array)
        {
          bf16x8 bh = ldsx(XthB, 16 * wv + l15, ko);
          bf16x8 bl = ldsx(XtlB, 16 * wv + l15, ko);
#pragma unroll
          for (int mt = 0; mt < 2; ++mt) {
            bf16x8 wh, wl;
            if constexpr (PW) {
              wh = *(const bf16x8*)&WkH[(size_t)(mt * 16 + l15) * 256 + kg];
              wl = *(const bf16x8*)&WkL[(size_t)(mt * 16 + l15) * 256 + kg];
            } else {
              load_split8(Wk + (size_t)(mt * 16 + l15) * 256 + kg, wh, wl);
            }
            kacc[mt] = MFMA16(wh, bh, kacc[mt]);
            kacc[mt] = MFMA16(wh, bl, kacc[mt]);
            kacc[mt] = MFMA16(wl, bh, kacc[mt]);
          }
        }
        // V (wave's 64 c-rows)
        __builtin_amdgcn_s_setprio(1);
#pragma unroll
        for (int mt = 0; mt < 4; ++mt) {
          bf16x8 wh, wl;
          if constexpr (PW) {
            wh = *(const bf16x8*)&WvH[(size_t)(64 * wv + mt * 16 + l15) * 256 + kg];
            wl = *(const bf16x8*)&WvL[(size_t)(64 * wv + mt * 16 + l15) * 256 + kg];
          } else {
            load_split8(Wv + (size_t)(64 * wv + mt * 16 + l15) * 256 + kg, wh, wl);
          }
#pragma unroll
          for (int nt = 0; nt < 4; ++nt) {
            vacc[mt][nt] = MFMA16(wh, xh[nt], vacc[mt][nt]);
            vacc[mt][nt] = MFMA16(wh, xl[nt], vacc[mt][nt]);
            vacc[mt][nt] = MFMA16(wl, xh[nt], vacc[mt][nt]);
          }
        }
        __builtin_amdgcn_s_setprio(0);
      }
      if (t < 3) {
        write_xlin();
      } else {
        // write K split to R3
        const int y = 16 * wv + l15;
#pragma unroll
        for (int mt = 0; mt < 2; ++mt)
#pragma unroll
          for (int r = 0; r < 4; ++r) {
            short hh, ll;
            split_val(kacc[mt][r], hh, ll);
            Kh[y * 32 + mt * 16 + 4 * g + r] = (ushort_t)hh;
            Kl[y * 32 + mt * 16 + 4 * g + r] = (ushort_t)ll;
          }
      }
      __syncthreads();
    }
  }

  // ===== phase 3: A = Q^T K (64x64) -> swizzled Ah/Al in R1 (Xth/Xtl dead) =====
  {
    const int y = 16 * wv + l15;
    bf16x8 kh = *(const bf16x8*)&Kh[y * 32 + 8 * g];
    bf16x8 kl = *(const bf16x8*)&Kl[y * 32 + 8 * g];
    f32x4 acc[4];
#pragma unroll
    for (int mt = 0; mt < 4; ++mt) acc[mt] = (f32x4){0.f, 0.f, 0.f, 0.f};
#pragma unroll
    for (int mt = 0; mt < 4; ++mt) {
      bf16x8 qh = *(const bf16x8*)&Qh[(mt * 16 + l15) * 32 + 8 * g];
      bf16x8 ql = *(const bf16x8*)&Ql[(mt * 16 + l15) * 32 + 8 * g];
      acc[mt] = MFMA16(qh, kh, acc[mt]);
      acc[mt] = MFMA16(qh, kl, acc[mt]);
      acc[mt] = MFMA16(ql, kh, acc[mt]);
    }
#pragma unroll
    for (int mt = 0; mt < 4; ++mt)
#pragma unroll
      for (int r = 0; r < 4; ++r) {
        short hh, ll;
        split_val(acc[mt][r], hh, ll);
        int xr = mt * 16 + 4 * g + r;
        *(ushort_t*)(AhB + swzb(xr, y * 2)) = (ushort_t)hh;
        *(ushort_t*)(AlB + swzb(xr, y * 2)) = (ushort_t)ll;
      }
  }
  __syncthreads();

  // ===== phase 4: Out = V * A^T, per 16-row c-tile via per-wave swizzled LDS (Vb overlays Xlin) =====
  {
    char* VhB = smem + OFF_R2 + wv * 4096;   // [16][128B] swz hi
    char* VlB = VhB + 2048;                  // [16][128B] swz lo
    const int cb = 64 * wv;
#pragma unroll
    for (int mt = 0; mt < 4; ++mt) {
#pragma unroll
      for (int nt = 0; nt < 4; ++nt)
#pragma unroll
        for (int r = 0; r < 4; ++r) {
          short hh, ll;
          split_val(vacc[mt][nt][r], hh, ll);
          int colb = (nt * 16 + l15) * 2;
          *(ushort_t*)(VhB + swzb(4 * g + r, colb)) = (ushort_t)hh;
          *(ushort_t*)(VlB + swzb(4 * g + r, colb)) = (ushort_t)ll;
        }
      f32x4 oacc[4];
#pragma unroll
      for (int nt = 0; nt < 4; ++nt) oacc[nt] = (f32x4){0.f, 0.f, 0.f, 0.f};
      __builtin_amdgcn_s_setprio(1);
#pragma unroll
      for (int ys = 0; ys < 2; ++ys) {
        const int yo = ys * 32 + 8 * g;
        bf16x8 vh8 = *(const bf16x8*)(VhB + swzb(l15, yo * 2));
        bf16x8 vl8 = *(const bf16x8*)(VlB + swzb(l15, yo * 2));
#pragma unroll
        for (int nt = 0; nt < 4; ++nt) {
          bf16x8 ah8 = *(const bf16x8*)(AhB + swzb(nt * 16 + l15, yo * 2));
          bf16x8 al8 = *(const bf16x8*)(AlB + swzb(nt * 16 + l15, yo * 2));
          oacc[nt] = MFMA16(vh8, ah8, oacc[nt]);
          oacc[nt] = MFMA16(vh8, al8, oacc[nt]);
          oacc[nt] = MFMA16(vl8, ah8, oacc[nt]);
        }
      }
      __builtin_amdgcn_s_setprio(0);
#pragma unroll
      for (int nt = 0; nt < 4; ++nt)
#pragma unroll
        for (int r = 0; r < 4; ++r)
          out[base + (size_t)(cb + mt * 16 + 4 * g + r) * DHW + nt * 16 + l15] = oacc[nt][r];
    }
  }
}

extern "C" void kernel_launch(void* const* d_in, const int* in_sizes, int n_in,
                              void* d_out, int out_size, void* d_ws, size_t ws_size,
                              hipStream_t stream)
{
  const float* x1 = (const float*)d_in[0];
  const float* x2 = (const float*)d_in[1];
  const float* Wq = (const float*)d_in[2];
  const float* bq = (const float*)d_in[3];
  const float* Wk = (const float*)d_in[4];
  const float* bk = (const float*)d_in[5];
  const float* Wv = (const float*)d_in[6];
  const float* bv = (const float*)d_in[7];
  float* out = (float*)d_out;

  if (d_ws && ws_size >= WS_W_BYTES) {
    ushort_t* ws = (ushort_t*)d_ws;
    hipLaunchKernelGGL(prep_w, dim3(320), dim3(256), 0, stream, Wq, Wk, Wv, ws);
    hipLaunchKernelGGL(xattn_fused<true>, dim3(NB * ND * NH), dim3(256), 0, stream,
                       x1, x2, Wq, bq, Wk, bk, Wv, bv, ws, out);
  } else {
    hipLaunchKernelGGL(xattn_fused<false>, dim3(NB * ND * NH), dim3(256), 0, stream,
                       x1, x2, Wq, bq, Wk, bk, Wv, bv, (const ushort_t*)nullptr, out);
  }
}

// Round 7
// 224.600 us; speedup vs baseline: 1.4229x; 1.0073x over previous
//
#include <hip/hip_runtime.h>

// Problem constants
#define NB   2
#define ND   16
#define NH   64
#define DHW  65536       // D*H*W
#define HW   4096        // H*W
#define CDHW 16777216    // C*D*H*W

typedef __attribute__((ext_vector_type(4))) float f32x4;
typedef __attribute__((ext_vector_type(8))) short bf16x8;
typedef unsigned short ushort_t;

#define MFMA16(a, b, c) __builtin_amdgcn_mfma_f32_16x16x32_bf16((a), (b), (c), 0, 0, 0)

// ---------------- LDS layout (bytes), total 65536 -> 2 blocks/CU ----------------
// buf0 [0,16384):       Xth0/Xtl0 [64][128B] swz     -> Ah/Al after loop
// buf1 [16384,32768):   Xth1/Xtl1                    -> Vb (4 waves x 4096 B) in PV
// wlin [32768,49152):   wave-private [16][64] f32 (4 KB per wave)
// QK   [49152,65536):   Qh/Ql/Kh/Kl [64][32] ushort (4 KB each)
#define OFF_B0H  0
#define OFF_B0L  8192
#define OFF_B1H  16384
#define OFF_B1L  24576
#define OFF_AH   0
#define OFF_AL   8192
#define OFF_VB   16384
#define OFF_WLIN 32768
#define OFF_QH   49152
#define OFF_QL   53248
#define OFF_KH   57344
#define OFF_KL   61440
#define SMEM_BYTES 65536

// ---------------- ws layout (ushort element offsets) ----------------
#define WS_WQH 0
#define WS_WQL 8192
#define WS_WKH 16384
#define WS_WKL 24576
#define WS_WVH 32768
#define WS_WVL 98304
#define WS_W_BYTES ((size_t)163840 * 2)

__device__ __forceinline__ void split_val(float f, short& h, short& l) {
  unsigned int u = __builtin_bit_cast(unsigned int, f);
  h = (short)(unsigned short)(u >> 16);
  float fh = __builtin_bit_cast(float, u & 0xffff0000u);
  float r = f - fh;
  l = (short)(unsigned short)(__builtin_bit_cast(unsigned int, r) >> 16);
}

__device__ __forceinline__ void load_split8(const float* __restrict__ p, bf16x8& h8, bf16x8& l8) {
  float4 a = *(const float4*)p;
  float4 b = *(const float4*)(p + 4);
  float f[8] = {a.x, a.y, a.z, a.w, b.x, b.y, b.z, b.w};
#pragma unroll
  for (int j = 0; j < 8; ++j) {
    short hh, ll;
    split_val(f[j], hh, ll);
    h8[j] = hh; l8[j] = ll;
  }
}

// byte offset in a [rows][128 B] XOR-swizzled tile (16 B slot granularity)
__device__ __forceinline__ int swzb(int row, int colb) {
  return row * 128 + (((colb) & ~15) ^ ((row & 7) << 4)) + ((colb) & 15);
}

// ---------------- weight pre-split kernel ----------------
__global__ void prep_w(const float* __restrict__ Wq, const float* __restrict__ Wk,
                       const float* __restrict__ Wv, ushort_t* __restrict__ ws) {
  int idx = blockIdx.x * 256 + threadIdx.x;
  const float* src; int off; ushort_t *H, *L;
  if (idx < 8192)       { src = Wq; off = idx;         H = ws + WS_WQH; L = ws + WS_WQL; }
  else if (idx < 16384) { src = Wk; off = idx - 8192;  H = ws + WS_WKH; L = ws + WS_WKL; }
  else if (idx < 81920) { src = Wv; off = idx - 16384; H = ws + WS_WVH; L = ws + WS_WVL; }
  else return;
  short h, l;
  split_val(src[off], h, l);
  H[off] = (ushort_t)h;
  L[off] = (ushort_t)l;
}

// ---------------- main fused kernel ----------------
template<bool PW>
__global__ __launch_bounds__(256, 2) void xattn_fused(
    const float* __restrict__ x1, const float* __restrict__ x2,
    const float* __restrict__ Wq, const float* __restrict__ bq,
    const float* __restrict__ Wk, const float* __restrict__ bk,
    const float* __restrict__ Wv, const float* __restrict__ bv,
    const ushort_t* __restrict__ wsp, float* __restrict__ out)
{
  extern __shared__ char smem[];
  const int tid  = threadIdx.x;
  const int lane = tid & 63;
  const int wv   = tid >> 6;
  const int l15  = lane & 15;
  const int g    = lane >> 4;

  // XCD-aware bijective swizzle: 2048 blocks % 8 == 0
  const int bid = blockIdx.x;
  const int grp = (bid & 7) * 256 + (bid >> 3);
  const int b   = grp >> 10;
  const int rem = grp & 1023;
  const int d   = rem >> 6;
  const int h   = rem & 63;
  const size_t base = (size_t)b * CDHW + (size_t)d * HW + (size_t)h * 64;

  const ushort_t* WqH = wsp + WS_WQH;
  const ushort_t* WqL = wsp + WS_WQL;
  const ushort_t* WkH = wsp + WS_WKH;
  const ushort_t* WkL = wsp + WS_WKL;
  const ushort_t* WvH = wsp + WS_WVH;
  const ushort_t* WvL = wsp + WS_WVL;

  float*    wlin = (float*)(smem + OFF_WLIN + wv * 4096);  // wave-private [16][64]
  ushort_t* Qh   = (ushort_t*)(smem + OFF_QH);
  ushort_t* Ql   = (ushort_t*)(smem + OFF_QL);
  ushort_t* Kh   = (ushort_t*)(smem + OFF_KH);
  ushort_t* Kl   = (ushort_t*)(smem + OFF_KL);

  const float* x1p = x1 + base;
  const float* x2p = x2 + base;
  auto tsrc = [&](int i) -> const float* {
    return (i < 4) ? (x1p + (size_t)i * 64 * DHW) : (x2p + (size_t)(i - 4) * 64 * DHW);
  };

  // staging regs: wave's 16 channels, 256 B-coalesced per channel
  float4 pf[4];
  auto issue_pf = [&](const float* __restrict__ src) {
#pragma unroll
    for (int i = 0; i < 4; ++i) {
      int ch = 16 * wv + g + 4 * i;
      pf[i] = *(const float4*)(src + (size_t)ch * DHW + 4 * l15);
    }
  };
  auto write_wlin = [&]() {
#pragma unroll
    for (int i = 0; i < 4; ++i)
      *(float4*)&wlin[(g + 4 * i) * 64 + 4 * l15] = pf[i];
  };
  // transpose + split own 16 channels into swizzled buf (row = lane = x, cols = strip)
  auto passB = [&](char* th, char* tl) {
#pragma unroll
    for (int bb = 0; bb < 2; ++bb) {
      int c0 = 8 * bb;                       // local channel octet
      bf16x8 h8, l8;
#pragma unroll
      for (int j = 0; j < 8; ++j) {
        float f = wlin[(c0 + j) * 64 + lane];
        short hh, ll;
        split_val(f, hh, ll);
        h8[j] = hh; l8[j] = ll;
      }
      int cg = 16 * wv + c0;                 // global channel within tile
      *(bf16x8*)(th + swzb(lane, cg * 2)) = h8;
      *(bf16x8*)(tl + swzb(lane, cg * 2)) = l8;
    }
  };
  auto ldsx = [&](const char* B, int row, int ko) -> bf16x8 {
    return *(const bf16x8*)(B + swzb(row, ko * 2));
  };

  char* bufH[2] = { smem + OFF_B0H, smem + OFF_B1H };
  char* bufL[2] = { smem + OFF_B0L, smem + OFF_B1L };

  // accumulators
  f32x4 qacc[2], kacc[2], vacc[4][4];
#pragma unroll
  for (int mt = 0; mt < 2; ++mt) {
    int r0 = mt * 16 + 4 * g;
    qacc[mt] = (f32x4){bq[r0], bq[r0 + 1], bq[r0 + 2], bq[r0 + 3]};
    kacc[mt] = (f32x4){bk[r0], bk[r0 + 1], bk[r0 + 2], bk[r0 + 3]};
  }
#pragma unroll
  for (int mt = 0; mt < 4; ++mt) {
    int r0 = 64 * wv + mt * 16 + 4 * g;
    f32x4 bb = (f32x4){bv[r0], bv[r0 + 1], bv[r0 + 2], bv[r0 + 3]};
#pragma unroll
    for (int nt = 0; nt < 4; ++nt) vacc[mt][nt] = bb;
  }

  // ===== prologue: tile0 staged to buf0; tile1 loads in flight =====
  issue_pf(tsrc(0));
  write_wlin();
  passB(bufH[0], bufL[0]);
  issue_pf(tsrc(1));

  // ===== half 1: tiles 0..3 (x1) -> Q; staging for t+1 in MFMA shadow =====
#pragma unroll
  for (int t = 0; t < 4; ++t) {
    __syncthreads();                        // buf[t&1] visible; buf[(t+1)&1] free
    // --- staging for tile t+1 (independent of MFMA below; scheduler interleaves)
    write_wlin();                           // pf(t+1) -> own wlin
    issue_pf(tsrc(t + 2));                  // pf(t+2) in flight
    passB(bufH[(t + 1) & 1], bufL[(t + 1) & 1]);
    // --- Q MFMA on buf[t&1]
#pragma unroll
    for (int ks = 0; ks < 2; ++ks) {
      const int ko = ks * 32 + 8 * g;
      const int kg = t * 64 + ko;
      bf16x8 bh = ldsx(bufH[t & 1], 16 * wv + l15, ko);
      bf16x8 bl = ldsx(bufL[t & 1], 16 * wv + l15, ko);
#pragma unroll
      for (int mt = 0; mt < 2; ++mt) {
        bf16x8 wh, wl;
        if constexpr (PW) {
          wh = *(const bf16x8*)&WqH[(size_t)(mt * 16 + l15) * 256 + kg];
          wl = *(const bf16x8*)&WqL[(size_t)(mt * 16 + l15) * 256 + kg];
        } else {
          load_split8(Wq + (size_t)(mt * 16 + l15) * 256 + kg, wh, wl);
        }
        qacc[mt] = MFMA16(wh, bh, qacc[mt]);
        qacc[mt] = MFMA16(wh, bl, qacc[mt]);
        qacc[mt] = MFMA16(wl, bh, qacc[mt]);
      }
    }
    if (t == 3) {
      const int x = 16 * wv + l15;
#pragma unroll
      for (int mt = 0; mt < 2; ++mt)
#pragma unroll
        for (int r = 0; r < 4; ++r) {
          short hh, ll;
          split_val(qacc[mt][r], hh, ll);
          Qh[x * 32 + mt * 16 + 4 * g + r] = (ushort_t)hh;
          Ql[x * 32 + mt * 16 + 4 * g + r] = (ushort_t)ll;
        }
    }
  }

  // ===== half 2: tiles 4..7 (x2) -> K + V =====
#pragma unroll
  for (int u = 0; u < 4; ++u) {
    __syncthreads();
    if (u < 3) {
      write_wlin();
      if (u < 2) issue_pf(tsrc(u + 6));
      passB(bufH[(u + 1) & 1], bufL[(u + 1) & 1]);
    }
    const char* th = bufH[u & 1];
    const char* tl = bufL[u & 1];
#pragma unroll
    for (int ks = 0; ks < 2; ++ks) {
      const int ko = ks * 32 + 8 * g;
      const int kg = u * 64 + ko;
      bf16x8 xh[4], xl[4];
#pragma unroll
      for (int nt = 0; nt < 4; ++nt) {
        xh[nt] = ldsx(th, nt * 16 + l15, ko);
        xl[nt] = ldsx(tl, nt * 16 + l15, ko);
      }
      // K (B-frag re-loaded explicitly)
      {
        bf16x8 bh = ldsx(th, 16 * wv + l15, ko);
        bf16x8 bl = ldsx(tl, 16 * wv + l15, ko);
#pragma unroll
        for (int mt = 0; mt < 2; ++mt) {
          bf16x8 wh, wl;
          if constexpr (PW) {
            wh = *(const bf16x8*)&WkH[(size_t)(mt * 16 + l15) * 256 + kg];
            wl = *(const bf16x8*)&WkL[(size_t)(mt * 16 + l15) * 256 + kg];
          } else {
            load_split8(Wk + (size_t)(mt * 16 + l15) * 256 + kg, wh, wl);
          }
          kacc[mt] = MFMA16(wh, bh, kacc[mt]);
          kacc[mt] = MFMA16(wh, bl, kacc[mt]);
          kacc[mt] = MFMA16(wl, bh, kacc[mt]);
        }
      }
      // V (wave's 64 c-rows)
      __builtin_amdgcn_s_setprio(1);
#pragma unroll
      for (int mt = 0; mt < 4; ++mt) {
        bf16x8 wh, wl;
        if constexpr (PW) {
          wh = *(const bf16x8*)&WvH[(size_t)(64 * wv + mt * 16 + l15) * 256 + kg];
          wl = *(const bf16x8*)&WvL[(size_t)(64 * wv + mt * 16 + l15) * 256 + kg];
        } else {
          load_split8(Wv + (size_t)(64 * wv + mt * 16 + l15) * 256 + kg, wh, wl);
        }
#pragma unroll
        for (int nt = 0; nt < 4; ++nt) {
          vacc[mt][nt] = MFMA16(wh, xh[nt], vacc[mt][nt]);
          vacc[mt][nt] = MFMA16(wh, xl[nt], vacc[mt][nt]);
          vacc[mt][nt] = MFMA16(wl, xh[nt], vacc[mt][nt]);
        }
      }
      __builtin_amdgcn_s_setprio(0);
    }
    if (u == 3) {
      const int y = 16 * wv + l15;
#pragma unroll
      for (int mt = 0; mt < 2; ++mt)
#pragma unroll
        for (int r = 0; r < 4; ++r) {
          short hh, ll;
          split_val(kacc[mt][r], hh, ll);
          Kh[y * 32 + mt * 16 + 4 * g + r] = (ushort_t)hh;
          Kl[y * 32 + mt * 16 + 4 * g + r] = (ushort_t)ll;
        }
    }
  }
  __syncthreads();   // K visible; buf reads done -> A may overlay buf0

  // ===== phase 3: A = Q^T K (64x64) -> swizzled Ah/Al (overlays buf0) =====
  {
    char* AhB = smem + OFF_AH;
    char* AlB = smem + OFF_AL;
    const int y = 16 * wv + l15;
    bf16x8 kh = *(const bf16x8*)&Kh[y * 32 + 8 * g];
    bf16x8 kl = *(const bf16x8*)&Kl[y * 32 + 8 * g];
    f32x4 acc[4];
#pragma unroll
    for (int mt = 0; mt < 4; ++mt) acc[mt] = (f32x4){0.f, 0.f, 0.f, 0.f};
#pragma unroll
    for (int mt = 0; mt < 4; ++mt) {
      bf16x8 qh = *(const bf16x8*)&Qh[(mt * 16 + l15) * 32 + 8 * g];
      bf16x8 ql = *(const bf16x8*)&Ql[(mt * 16 + l15) * 32 + 8 * g];
      acc[mt] = MFMA16(qh, kh, acc[mt]);
      acc[mt] = MFMA16(qh, kl, acc[mt]);
      acc[mt] = MFMA16(ql, kh, acc[mt]);
    }
#pragma unroll
    for (int mt = 0; mt < 4; ++mt)
#pragma unroll
      for (int r = 0; r < 4; ++r) {
        short hh, ll;
        split_val(acc[mt][r], hh, ll);
        int xr = mt * 16 + 4 * g + r;
        *(ushort_t*)(AhB + swzb(xr, y * 2)) = (ushort_t)hh;
        *(ushort_t*)(AlB + swzb(xr, y * 2)) = (ushort_t)ll;
      }
  }
  __syncthreads();

  // ===== phase 4: Out = V * A^T per 16-row c-tile (Vb overlays buf1) =====
  {
    const char* AhB = smem + OFF_AH;
    const char* AlB = smem + OFF_AL;
    char* VhB = smem + OFF_VB + wv * 4096;   // [16][128B] swz hi
    char* VlB = VhB + 2048;                  // lo
    const int cb = 64 * wv;
#pragma unroll
    for (int mt = 0; mt < 4; ++mt) {
#pragma unroll
      for (int nt = 0; nt < 4; ++nt)
#pragma unroll
        for (int r = 0; r < 4; ++r) {
          short hh, ll;
          split_val(vacc[mt][nt][r], hh, ll);
          int colb = (nt * 16 + l15) * 2;
          *(ushort_t*)(VhB + swzb(4 * g + r, colb)) = (ushort_t)hh;
          *(ushort_t*)(VlB + swzb(4 * g + r, colb)) = (ushort_t)ll;
        }
      f32x4 oacc[4];
#pragma unroll
      for (int nt = 0; nt < 4; ++nt) oacc[nt] = (f32x4){0.f, 0.f, 0.f, 0.f};
      __builtin_amdgcn_s_setprio(1);
#pragma unroll
      for (int ys = 0; ys < 2; ++ys) {
        const int yo = ys * 32 + 8 * g;
        bf16x8 vh8 = *(const bf16x8*)(VhB + swzb(l15, yo * 2));
        bf16x8 vl8 = *(const bf16x8*)(VlB + swzb(l15, yo * 2));
#pragma unroll
        for (int nt = 0; nt < 4; ++nt) {
          bf16x8 ah8 = *(const bf16x8*)(AhB + swzb(nt * 16 + l15, yo * 2));
          bf16x8 al8 = *(const bf16x8*)(AlB + swzb(nt * 16 + l15, yo * 2));
          oacc[nt] = MFMA16(vh8, ah8, oacc[nt]);
          oacc[nt] = MFMA16(vh8, al8, oacc[nt]);
          oacc[nt] = MFMA16(vl8, ah8, oacc[nt]);
        }
      }
      __builtin_amdgcn_s_setprio(0);
#pragma unroll
      for (int nt = 0; nt < 4; ++nt)
#pragma unroll
        for (int r = 0; r < 4; ++r)
          out[base + (size_t)(cb + mt * 16 + 4 * g + r) * DHW + nt * 16 + l15] = oacc[nt][r];
    }
  }
}

extern "C" void kernel_launch(void* const* d_in, const int* in_sizes, int n_in,
                              void* d_out, int out_size, void* d_ws, size_t ws_size,
                              hipStream_t stream)
{
  const float* x1 = (const float*)d_in[0];
  const float* x2 = (const float*)d_in[1];
  const float* Wq = (const float*)d_in[2];
  const float* bq = (const float*)d_in[3];
  const float* Wk = (const float*)d_in[4];
  const float* bk = (const float*)d_in[5];
  const float* Wv = (const float*)d_in[6];
  const float* bv = (const float*)d_in[7];
  float* out = (float*)d_out;

  if (d_ws && ws_size >= WS_W_BYTES) {
    ushort_t* ws = (ushort_t*)d_ws;
    (void)hipFuncSetAttribute((const void*)xattn_fused<true>,
                              hipFuncAttributeMaxDynamicSharedMemorySize, SMEM_BYTES);
    hipLaunchKernelGGL(prep_w, dim3(320), dim3(256), 0, stream, Wq, Wk, Wv, ws);
    hipLaunchKernelGGL(xattn_fused<true>, dim3(NB * ND * NH), dim3(256), SMEM_BYTES, stream,
                       x1, x2, Wq, bq, Wk, bk, Wv, bv, ws, out);
  } else {
    (void)hipFuncSetAttribute((const void*)xattn_fused<false>,
                              hipFuncAttributeMaxDynamicSharedMemorySize, SMEM_BYTES);
    hipLaunchKernelGGL(xattn_fused<false>, dim3(NB * ND * NH), dim3(256), SMEM_BYTES, stream,
                       x1, x2, Wq, bq, Wk, bk, Wv, bv, (const ushort_t*)nullptr, out);
  }
}